// Round 3
// baseline (800.993 us; speedup 1.0000x reference)
//
#include <hip/hip_runtime.h>

// Problem constants (match reference): B=256, S=1024, E=256, C=4, NB=4
#define BB 256
#define SS 1024
#define EE 256
#define CC 4

#define SEGS 8                 // segments per (b,n) slab
#define SEGROWS (SS / SEGS)    // 128 rows per segment
#define NBLK1 (BB * 4 * SEGS)  // 8192 phase-1 blocks

// ---------------------------------------------------------------------------
// Phase 1 (two-stage path): one block per (batch, branch, segment).
// 256 threads = 4 waves; tid = sl*64 + e4. Thread streams 32 rows (stride 4)
// of its 128-row segment with the R1-proven 2-load/2-acc loop (VGPR ~36,
// 8 waves/SIMD). 8192 blocks over 256 CUs = ~32 queued vs ~8 resident per CU:
// fast CUs backfill with more blocks, removing the exact-fit straggler tail
// that capped the 1024-block version at ~4.4 TB/s delivered (occ ~55%).
// Output: per-segment pooled partial sums (raw, un-normalized) to ws.
// ---------------------------------------------------------------------------
__global__ __launch_bounds__(256) void pool_partial_kernel(
    const float* __restrict__ x0, const float* __restrict__ x1,
    const float* __restrict__ x2, const float* __restrict__ x3,
    float* __restrict__ ws)
{
    const int g   = blockIdx.x;      // 0..NBLK1-1
    const int bn  = g >> 3;          // (b,n) slab
    const int seg = g & (SEGS - 1);  // segment within slab
    const int b   = bn >> 2;
    const int n   = bn & 3;
    const float* __restrict__ x =
        (n == 0) ? x0 : (n == 1) ? x1 : (n == 2) ? x2 : x3;

    const int tid = threadIdx.x;
    const int e4  = tid & 63;   // float4 column
    const int sl  = tid >> 6;   // seq slice within segment (0..3)

    const size_t base = (size_t)b * ((size_t)SS * EE)
                      + (size_t)(seg * SEGROWS + sl) * EE
                      + (size_t)(e4 << 2);
    const float4* __restrict__ p = (const float4*)(x + base);
    // stepping 4 rows advances 4*EE floats = 4*EE/4 float4s
    const size_t step = (size_t)4 * (EE / 4);   // 256 float4

    float4 a0 = make_float4(0.f, 0.f, 0.f, 0.f);
    float4 a1 = make_float4(0.f, 0.f, 0.f, 0.f);
    // SEGROWS/4 = 32 rows per thread; R1's loop shape (best measured codegen)
    #pragma unroll 4
    for (int i = 0; i < SEGROWS / 4; i += 2) {
        float4 v0 = p[(size_t)i * step];
        float4 v1 = p[(size_t)(i + 1) * step];
        a0.x += v0.x; a0.y += v0.y; a0.z += v0.z; a0.w += v0.w;
        a1.x += v1.x; a1.y += v1.y; a1.z += v1.z; a1.w += v1.w;
    }
    float4 acc;
    acc.x = a0.x + a1.x; acc.y = a0.y + a1.y;
    acc.z = a0.z + a1.z; acc.w = a0.w + a1.w;

    __shared__ float4 red[256];
    red[tid] = acc;
    __syncthreads();

    if (tid < 64) {
        float4 s0 = red[tid];
        float4 s1 = red[tid + 64];
        float4 s2 = red[tid + 128];
        float4 s3 = red[tid + 192];
        float4 part;
        part.x = (s0.x + s1.x) + (s2.x + s3.x);
        part.y = (s0.y + s1.y) + (s2.y + s3.y);
        part.z = (s0.z + s1.z) + (s2.z + s3.z);
        part.w = (s0.w + s1.w) + (s2.w + s3.w);
        // contiguous 1 KB store per block
        ((float4*)ws)[(size_t)g * 64 + tid] = part;
    }
}

// ---------------------------------------------------------------------------
// Phase 2: one 64-thread block per (b,n). Sum the 8 segment partials,
// normalize, dot with W (4 classes), butterfly-reduce, relu+argmax, vote.
// Reads 8 MB total — ~10 µs including launch.
// ---------------------------------------------------------------------------
__global__ __launch_bounds__(64) void combine_vote_kernel(
    const float* __restrict__ ws, const float* __restrict__ W,
    const float* __restrict__ bias, float* __restrict__ out)
{
    const int bn  = blockIdx.x;   // 0..1023
    const int b   = bn >> 2;
    const int tid = threadIdx.x;  // 0..63 (= e4)

    const float4* __restrict__ ws4 = (const float4*)ws;
    float4 pool = make_float4(0.f, 0.f, 0.f, 0.f);
    #pragma unroll
    for (int seg = 0; seg < SEGS; ++seg) {
        float4 v = ws4[(size_t)(bn * SEGS + seg) * 64 + tid];
        pool.x += v.x; pool.y += v.y; pool.z += v.z; pool.w += v.w;
    }
    const float inv = 1.0f / (float)SS;
    pool.x *= inv; pool.y *= inv; pool.z *= inv; pool.w *= inv;

    const float4* __restrict__ W4 = (const float4*)W;  // [C][64] float4
    float d0, d1, d2, d3;
    {
        float4 w0 = W4[0 * 64 + tid];
        float4 w1 = W4[1 * 64 + tid];
        float4 w2 = W4[2 * 64 + tid];
        float4 w3 = W4[3 * 64 + tid];
        d0 = pool.x * w0.x + pool.y * w0.y + pool.z * w0.z + pool.w * w0.w;
        d1 = pool.x * w1.x + pool.y * w1.y + pool.z * w1.z + pool.w * w1.w;
        d2 = pool.x * w2.x + pool.y * w2.y + pool.z * w2.z + pool.w * w2.w;
        d3 = pool.x * w3.x + pool.y * w3.y + pool.z * w3.z + pool.w * w3.w;
    }
    #pragma unroll
    for (int off = 32; off >= 1; off >>= 1) {
        d0 += __shfl_down(d0, off, 64);
        d1 += __shfl_down(d1, off, 64);
        d2 += __shfl_down(d2, off, 64);
        d3 += __shfl_down(d3, off, 64);
    }

    if (tid == 0) {
        float l0 = fmaxf(d0 + bias[0], 0.f);
        float l1 = fmaxf(d1 + bias[1], 0.f);
        float l2 = fmaxf(d2 + bias[2], 0.f);
        float l3 = fmaxf(d3 + bias[3], 0.f);
        // first-max-wins argmax (matches jnp.argmax tie semantics)
        int pred = 0; float best = l0;
        if (l1 > best) { best = l1; pred = 1; }
        if (l2 > best) { best = l2; pred = 2; }
        if (l3 > best) { best = l3; pred = 3; }
        atomicAdd(&out[b * CC + pred], 0.25f);  // exact in fp32
    }
}

// ---------------------------------------------------------------------------
// Fallback single-kernel path (R1 version) if the workspace is too small.
// ---------------------------------------------------------------------------
__global__ __launch_bounds__(512) void pool_vote_kernel(
    const float* __restrict__ x0, const float* __restrict__ x1,
    const float* __restrict__ x2, const float* __restrict__ x3,
    const float* __restrict__ W, const float* __restrict__ bias,
    float* __restrict__ out)
{
    const int bn = blockIdx.x;
    const int b  = bn >> 2;
    const int n  = bn & 3;
    const float* __restrict__ x =
        (n == 0) ? x0 : (n == 1) ? x1 : (n == 2) ? x2 : x3;

    const int tid = threadIdx.x;
    const int e4  = tid & 63;
    const int sl  = tid >> 6;

    const size_t base = (size_t)b * ((size_t)SS * EE)
                      + (size_t)sl * EE
                      + (size_t)(e4 << 2);
    const float4* __restrict__ p = (const float4*)(x + base);
    const size_t step = (size_t)8 * (EE / 4);

    float4 a0 = make_float4(0.f, 0.f, 0.f, 0.f);
    float4 a1 = make_float4(0.f, 0.f, 0.f, 0.f);
    #pragma unroll 4
    for (int i = 0; i < SS / 8; i += 2) {
        float4 v0 = p[(size_t)i * step];
        float4 v1 = p[(size_t)(i + 1) * step];
        a0.x += v0.x; a0.y += v0.y; a0.z += v0.z; a0.w += v0.w;
        a1.x += v1.x; a1.y += v1.y; a1.z += v1.z; a1.w += v1.w;
    }
    float4 acc;
    acc.x = a0.x + a1.x; acc.y = a0.y + a1.y;
    acc.z = a0.z + a1.z; acc.w = a0.w + a1.w;

    __shared__ float4 red[512];
    red[tid] = acc;
    __syncthreads();

    if (tid < 64) {
        const float inv = 1.0f / (float)SS;
        float4 s0 = red[tid];
        float4 s1 = red[tid + 64];
        float4 s2 = red[tid + 128];
        float4 s3 = red[tid + 192];
        float4 s4 = red[tid + 256];
        float4 s5 = red[tid + 320];
        float4 s6 = red[tid + 384];
        float4 s7 = red[tid + 448];
        float4 pool;
        pool.x = ((s0.x + s1.x) + (s2.x + s3.x)) + ((s4.x + s5.x) + (s6.x + s7.x));
        pool.y = ((s0.y + s1.y) + (s2.y + s3.y)) + ((s4.y + s5.y) + (s6.y + s7.y));
        pool.z = ((s0.z + s1.z) + (s2.z + s3.z)) + ((s4.z + s5.z) + (s6.z + s7.z));
        pool.w = ((s0.w + s1.w) + (s2.w + s3.w)) + ((s4.w + s5.w) + (s6.w + s7.w));
        pool.x *= inv; pool.y *= inv; pool.z *= inv; pool.w *= inv;

        const float4* __restrict__ W4 = (const float4*)W;
        float d0, d1, d2, d3;
        {
            float4 w0 = W4[0 * 64 + tid];
            float4 w1 = W4[1 * 64 + tid];
            float4 w2 = W4[2 * 64 + tid];
            float4 w3 = W4[3 * 64 + tid];
            d0 = pool.x * w0.x + pool.y * w0.y + pool.z * w0.z + pool.w * w0.w;
            d1 = pool.x * w1.x + pool.y * w1.y + pool.z * w1.z + pool.w * w1.w;
            d2 = pool.x * w2.x + pool.y * w2.y + pool.z * w2.z + pool.w * w2.w;
            d3 = pool.x * w3.x + pool.y * w3.y + pool.z * w3.z + pool.w * w3.w;
        }
        #pragma unroll
        for (int off = 32; off >= 1; off >>= 1) {
            d0 += __shfl_down(d0, off, 64);
            d1 += __shfl_down(d1, off, 64);
            d2 += __shfl_down(d2, off, 64);
            d3 += __shfl_down(d3, off, 64);
        }

        if (tid == 0) {
            float l0 = fmaxf(d0 + bias[0], 0.f);
            float l1 = fmaxf(d1 + bias[1], 0.f);
            float l2 = fmaxf(d2 + bias[2], 0.f);
            float l3 = fmaxf(d3 + bias[3], 0.f);
            int pred = 0; float best = l0;
            if (l1 > best) { best = l1; pred = 1; }
            if (l2 > best) { best = l2; pred = 2; }
            if (l3 > best) { best = l3; pred = 3; }
            atomicAdd(&out[b * CC + pred], 0.25f);
        }
    }
}

extern "C" void kernel_launch(void* const* d_in, const int* in_sizes, int n_in,
                              void* d_out, int out_size, void* d_ws, size_t ws_size,
                              hipStream_t stream) {
    const float* x_acc  = (const float*)d_in[0];
    const float* x_bvp  = (const float*)d_in[1];
    const float* x_eda  = (const float*)d_in[2];
    const float* x_temp = (const float*)d_in[3];
    const float* W      = (const float*)d_in[4];
    const float* bias   = (const float*)d_in[5];
    float* out = (float*)d_out;

    // d_out is poisoned 0xAA before every timed launch; zero it (capture-safe).
    hipMemsetAsync(out, 0, (size_t)out_size * sizeof(float), stream);

    const size_t ws_need = (size_t)NBLK1 * 64 * sizeof(float4);  // 8 MB
    if (d_ws != nullptr && ws_size >= ws_need) {
        float* ws = (float*)d_ws;
        pool_partial_kernel<<<dim3(NBLK1), dim3(256), 0, stream>>>(
            x_acc, x_bvp, x_eda, x_temp, ws);
        combine_vote_kernel<<<dim3(BB * 4), dim3(64), 0, stream>>>(
            ws, W, bias, out);
    } else {
        pool_vote_kernel<<<dim3(BB * 4), dim3(512), 0, stream>>>(
            x_acc, x_bvp, x_eda, x_temp, W, bias, out);
    }
}

// Round 4
// 761.179 us; speedup vs baseline: 1.0523x; 1.0523x over previous
//
#include <hip/hip_runtime.h>

// Problem constants (match reference): B=256, S=1024, E=256, C=4, NB=4
#define BB 256
#define SS 1024
#define EE 256
#define CC 4

typedef float f4 __attribute__((ext_vector_type(4)));

// One block per (batch, branch). 512 threads = 8 waves. (R1 config — best
// measured: 230 us. R3's 8192-block two-stage split regressed to 250+10 us
// and falsified the straggler theory: occupancy 80% with identical BW.)
//   tid = sl*64 + e4 :  e4 in [0,64) owns float4 at embed offset e4*4,
//                       sl in [0,8) owns seq positions s = sl, sl+8, ...
// R4 change: streaming loads are NONTEMPORAL (global_load_dwordx4 nt) —
// 1.07 GB single-pass stream gains nothing from L1/L2/L3 allocation and the
// allocate/evict churn is the last candidate for the 4.3 vs ~6.3 TB/s gap.
// Phase 2: LDS combine of the 8 seq-slices.
// Phase 3: wave 0 computes the 4 class dots + bias + relu + argmax, votes
//          via atomicAdd of exact 0.25f into the (memset-zeroed) output.
__global__ __launch_bounds__(512) void pool_vote_kernel(
    const float* __restrict__ x0, const float* __restrict__ x1,
    const float* __restrict__ x2, const float* __restrict__ x3,
    const float* __restrict__ W, const float* __restrict__ bias,
    float* __restrict__ out)
{
    const int bn = blockIdx.x;
    const int b  = bn >> 2;
    const int n  = bn & 3;
    const float* __restrict__ x =
        (n == 0) ? x0 : (n == 1) ? x1 : (n == 2) ? x2 : x3;

    const int tid = threadIdx.x;
    const int e4  = tid & 63;   // float4 column
    const int sl  = tid >> 6;   // seq slice (0..7)

    // base element offset: batch slab + first seq row of this slice + embed col
    const size_t base = (size_t)b * ((size_t)SS * EE)
                      + (size_t)sl * EE
                      + (size_t)(e4 << 2);
    const f4* __restrict__ p = (const f4*)(x + base);
    // stepping s by 8 rows advances 8*EE floats = 8*EE/4 float4s
    const size_t step = (size_t)8 * (EE / 4);   // 512 float4

    f4 a0 = (f4)(0.f);
    f4 a1 = (f4)(0.f);
    // SS/8 = 128 rows per thread; R1's proven 2-load/2-acc loop shape,
    // loads marked nontemporal.
    #pragma unroll 4
    for (int i = 0; i < SS / 8; i += 2) {
        f4 v0 = __builtin_nontemporal_load(p + (size_t)i * step);
        f4 v1 = __builtin_nontemporal_load(p + (size_t)(i + 1) * step);
        a0 += v0;
        a1 += v1;
    }
    f4 acc = a0 + a1;

    __shared__ f4 red[512];
    red[tid] = acc;
    __syncthreads();

    if (tid < 64) {
        const float inv = 1.0f / (float)SS;
        f4 s0 = red[tid];
        f4 s1 = red[tid + 64];
        f4 s2 = red[tid + 128];
        f4 s3 = red[tid + 192];
        f4 s4 = red[tid + 256];
        f4 s5 = red[tid + 320];
        f4 s6 = red[tid + 384];
        f4 s7 = red[tid + 448];
        f4 pool = (((s0 + s1) + (s2 + s3)) + ((s4 + s5) + (s6 + s7))) * inv;

        // per-lane partial dot for each of the 4 classes
        const f4* __restrict__ W4 = (const f4*)W;  // [C][64] f4
        f4 w0 = W4[0 * 64 + tid];
        f4 w1 = W4[1 * 64 + tid];
        f4 w2 = W4[2 * 64 + tid];
        f4 w3 = W4[3 * 64 + tid];
        float d0 = pool.x * w0.x + pool.y * w0.y + pool.z * w0.z + pool.w * w0.w;
        float d1 = pool.x * w1.x + pool.y * w1.y + pool.z * w1.z + pool.w * w1.w;
        float d2 = pool.x * w2.x + pool.y * w2.y + pool.z * w2.z + pool.w * w2.w;
        float d3 = pool.x * w3.x + pool.y * w3.y + pool.z * w3.z + pool.w * w3.w;

        // 64-lane butterfly reduction (tid<64 is exactly wave 0)
        #pragma unroll
        for (int off = 32; off >= 1; off >>= 1) {
            d0 += __shfl_down(d0, off, 64);
            d1 += __shfl_down(d1, off, 64);
            d2 += __shfl_down(d2, off, 64);
            d3 += __shfl_down(d3, off, 64);
        }

        if (tid == 0) {
            float l0 = fmaxf(d0 + bias[0], 0.f);
            float l1 = fmaxf(d1 + bias[1], 0.f);
            float l2 = fmaxf(d2 + bias[2], 0.f);
            float l3 = fmaxf(d3 + bias[3], 0.f);
            // first-max-wins argmax (matches jnp.argmax tie semantics,
            // incl. the all-negative -> all-relu-zero -> pred 0 case)
            int pred = 0; float best = l0;
            if (l1 > best) { best = l1; pred = 1; }
            if (l2 > best) { best = l2; pred = 2; }
            if (l3 > best) { best = l3; pred = 3; }
            atomicAdd(&out[b * CC + pred], 0.25f);  // exact in fp32
        }
    }
}

extern "C" void kernel_launch(void* const* d_in, const int* in_sizes, int n_in,
                              void* d_out, int out_size, void* d_ws, size_t ws_size,
                              hipStream_t stream) {
    const float* x_acc  = (const float*)d_in[0];
    const float* x_bvp  = (const float*)d_in[1];
    const float* x_eda  = (const float*)d_in[2];
    const float* x_temp = (const float*)d_in[3];
    const float* W      = (const float*)d_in[4];
    const float* bias   = (const float*)d_in[5];
    float* out = (float*)d_out;

    // d_out is poisoned 0xAA before every timed launch; zero it (capture-safe).
    hipMemsetAsync(out, 0, (size_t)out_size * sizeof(float), stream);

    pool_vote_kernel<<<dim3(BB * 4), dim3(512), 0, stream>>>(
        x_acc, x_bvp, x_eda, x_temp, W, bias, out);
}